// Round 1
// baseline (2403.499 us; speedup 1.0000x reference)
//
#include <hip/hip_runtime.h>

#define CH 256
#define KC 8192
#define NT 32768

#define TM 64          // tokens per block tile
#define TK 128         // codes per block tile
#define BKC 16         // channel chunk staged in LDS
#define XS_STRIDE 68   // 64 + 4 pad (keeps 16B alignment, breaks bank stride)
#define CS_STRIDE 132  // 128 + 4 pad

// ---------------------------------------------------------------------------
// Kernel 1: codebook = ces / clip(usage, 1e-5); cb_sq[k] = sum_c cb^2
// Also initializes EMA outputs: new_usage = (1-s)*usage, new_ces = (1-s)*ces,
// and zeroes the loss accumulator (d_ws is poisoned 0xAA each launch).
// ---------------------------------------------------------------------------
__global__ void k_codebook(const float* __restrict__ usage,
                           const float* __restrict__ ces,
                           float* __restrict__ cbook,
                           float* __restrict__ cbsq,
                           float* __restrict__ out_usage,
                           float* __restrict__ out_ces,
                           float* __restrict__ loss_acc) {
    const float s = 0.01f;
    const float oms = 1.0f - s;     // match reference's fp32 arithmetic
    int k = blockIdx.x;
    int c = threadIdx.x;
    float u  = usage[k];
    float uc = fmaxf(u, 1e-5f);
    float v  = ces[k * CH + c];
    float cb = v / uc;
    cbook[k * CH + c]   = cb;
    out_ces[k * CH + c] = oms * v;

    float p = cb * cb;
    #pragma unroll
    for (int off = 32; off; off >>= 1) p += __shfl_down(p, off);
    __shared__ float ps[4];
    int lane = c & 63, w = c >> 6;
    if (lane == 0) ps[w] = p;
    __syncthreads();
    if (c == 0) {
        cbsq[k] = ps[0] + ps[1] + ps[2] + ps[3];
        out_usage[k] = oms * u;
    }
    if (blockIdx.x == 0 && c == 0) loss_acc[0] = 0.0f;
}

// ---------------------------------------------------------------------------
// Kernel 2: fp32 GEMM-shaped argmin.
// Block tile: TM=64 tokens x TK=128 codes, staged over C in BKC=16 chunks.
// 256 threads as 16(tx: codes) x 16(ty: tokens); each thread: 4 tokens x 8
// codes = 32 fp32 accumulators. score = cb_sq[j] - 2*dot(cb_j, x_n); running
// argmin kept per thread, reduced across tx via LDS at the end.
// ---------------------------------------------------------------------------
__launch_bounds__(256, 2)
__global__ void k_argmin(const float* __restrict__ emb,
                         const float* __restrict__ cbook,
                         const float* __restrict__ cbsq,
                         int*   __restrict__ codes,
                         float* __restrict__ codes_f) {
    __shared__ __align__(16) float xs[BKC * XS_STRIDE];
    __shared__ __align__(16) float cs[BKC * CS_STRIDE];
    __shared__ float rv[TM * 17];
    __shared__ int   ri[TM * 17];

    const int t  = threadIdx.x;
    const int tx = t & 15;         // code group 0..15 (8 codes each)
    const int ty = t >> 4;         // token group 0..15 (4 tokens each)
    const int n0 = blockIdx.x * TM;

    const int mload = t >> 2;      // 0..63: row loaded by this thread
    const int cv    = (t & 3) * 4; // 0,4,8,12: channel sub-offset

    float minv[4];
    int   mini[4];
    #pragma unroll
    for (int a = 0; a < 4; ++a) { minv[a] = 3.402823466e38f; mini[a] = 0; }

    for (int jt = 0; jt < KC; jt += TK) {
        float acc[4][8];
        #pragma unroll
        for (int a = 0; a < 4; ++a)
            #pragma unroll
            for (int b = 0; b < 8; ++b) acc[a][b] = 0.0f;

        #pragma unroll 1
        for (int c0 = 0; c0 < CH; c0 += BKC) {
            // global loads (issued before the barrier to overlap)
            float4 xv = *(const float4*)&emb  [(n0 + mload)      * CH + c0 + cv];
            float4 c1 = *(const float4*)&cbook[(jt + mload)      * CH + c0 + cv];
            float4 c2 = *(const float4*)&cbook[(jt + 64 + mload) * CH + c0 + cv];
            __syncthreads();  // previous stage's LDS reads done
            xs[(cv + 0) * XS_STRIDE + mload] = xv.x;
            xs[(cv + 1) * XS_STRIDE + mload] = xv.y;
            xs[(cv + 2) * XS_STRIDE + mload] = xv.z;
            xs[(cv + 3) * XS_STRIDE + mload] = xv.w;
            cs[(cv + 0) * CS_STRIDE + mload] = c1.x;
            cs[(cv + 1) * CS_STRIDE + mload] = c1.y;
            cs[(cv + 2) * CS_STRIDE + mload] = c1.z;
            cs[(cv + 3) * CS_STRIDE + mload] = c1.w;
            cs[(cv + 0) * CS_STRIDE + 64 + mload] = c2.x;
            cs[(cv + 1) * CS_STRIDE + 64 + mload] = c2.y;
            cs[(cv + 2) * CS_STRIDE + 64 + mload] = c2.z;
            cs[(cv + 3) * CS_STRIDE + 64 + mload] = c2.w;
            __syncthreads();

            #pragma unroll
            for (int kc = 0; kc < BKC; ++kc) {
                float4 xa  = *(const float4*)&xs[kc * XS_STRIDE + ty * 4];
                float4 ca  = *(const float4*)&cs[kc * CS_STRIDE + tx * 8];
                float4 cb2 = *(const float4*)&cs[kc * CS_STRIDE + tx * 8 + 4];
                float xr[4] = {xa.x, xa.y, xa.z, xa.w};
                float cr[8] = {ca.x, ca.y, ca.z, ca.w, cb2.x, cb2.y, cb2.z, cb2.w};
                #pragma unroll
                for (int a = 0; a < 4; ++a)
                    #pragma unroll
                    for (int b = 0; b < 8; ++b)
                        acc[a][b] = fmaf(xr[a], cr[b], acc[a][b]);
            }
        }

        // fold this code tile into the running argmin
        #pragma unroll
        for (int b = 0; b < 8; ++b) {
            int   j  = jt + tx * 8 + b;
            float sq = cbsq[j];
            #pragma unroll
            for (int a = 0; a < 4; ++a) {
                float sc = sq - 2.0f * acc[a][b];
                if (sc < minv[a]) { minv[a] = sc; mini[a] = j; }
            }
        }
    }

    __syncthreads();
    #pragma unroll
    for (int a = 0; a < 4; ++a) {
        rv[(ty * 4 + a) * 17 + tx] = minv[a];
        ri[(ty * 4 + a) * 17 + tx] = mini[a];
    }
    __syncthreads();
    if (t < TM) {
        float bv = rv[t * 17];
        int   bi = ri[t * 17];
        #pragma unroll 1
        for (int i = 1; i < 16; ++i) {
            float v = rv[t * 17 + i];
            int   x = ri[t * 17 + i];
            if (v < bv || (v == bv && x < bi)) { bv = v; bi = x; }
        }
        codes[n0 + t]   = bi;
        codes_f[n0 + t] = (float)bi;
    }
}

// ---------------------------------------------------------------------------
// Kernel 3: gather + straight-through + loss partials + EMA scatter
// ---------------------------------------------------------------------------
__global__ void k_gather(const float* __restrict__ emb,
                         const float* __restrict__ cbook,
                         const int* __restrict__ codes,
                         float* __restrict__ out_eq,
                         float* __restrict__ out_usage,
                         float* __restrict__ out_ces,
                         float* __restrict__ loss_acc) {
    const float s = 0.01f;
    int n = blockIdx.x;
    int c = threadIdx.x;
    int k = codes[n];
    float e  = emb[n * CH + c];
    float q  = cbook[k * CH + c];
    float eq = e + (q - e);
    out_eq[n * CH + c] = eq;
    atomicAdd(&out_ces[k * CH + c], s * e);

    float d = eq - e;
    float p = d * d;
    #pragma unroll
    for (int off = 32; off; off >>= 1) p += __shfl_down(p, off);
    __shared__ float ps[4];
    int lane = c & 63, w = c >> 6;
    if (lane == 0) ps[w] = p;
    __syncthreads();
    if (c == 0) {
        atomicAdd(loss_acc, ps[0] + ps[1] + ps[2] + ps[3]);
        atomicAdd(&out_usage[k], s);
    }
}

// ---------------------------------------------------------------------------
// Kernel 4: finalize loss (mean over N*C = 2^23 elements; reciprocal exact)
// ---------------------------------------------------------------------------
__global__ void k_final(const float* __restrict__ loss_acc,
                        float* __restrict__ out_loss) {
    out_loss[0] = loss_acc[0] * (1.0f / 8388608.0f);
}

extern "C" void kernel_launch(void* const* d_in, const int* in_sizes, int n_in,
                              void* d_out, int out_size, void* d_ws, size_t ws_size,
                              hipStream_t stream) {
    const float* emb   = (const float*)d_in[0];  // [32768, 256]
    const float* usage = (const float*)d_in[1];  // [8192]
    const float* ces   = (const float*)d_in[2];  // [8192, 256]

    float* out      = (float*)d_out;
    float* o_codes  = out;                       // 32768
    float* o_eq     = out + NT;                  // 8388608
    float* o_loss   = o_eq + (size_t)NT * CH;    // 1
    float* o_usage  = o_loss + 1;                // 8192
    float* o_ces    = o_usage + KC;              // 2097152

    float* ws       = (float*)d_ws;
    float* cbook    = ws;                        // KC*CH floats
    float* cbsq     = cbook + (size_t)KC * CH;   // KC floats
    int*   codes    = (int*)(cbsq + KC);         // NT ints
    float* loss_acc = (float*)(codes + NT);      // 1 float

    k_codebook<<<KC, CH, 0, stream>>>(usage, ces, cbook, cbsq, o_usage, o_ces, loss_acc);
    k_argmin<<<NT / TM, 256, 0, stream>>>(emb, cbook, cbsq, codes, o_codes);
    k_gather<<<NT, CH, 0, stream>>>(emb, cbook, codes, o_eq, o_usage, o_ces, loss_acc);
    k_final<<<1, 1, 0, stream>>>(loss_acc, o_loss);
}

// Round 2
// 996.798 us; speedup vs baseline: 2.4112x; 2.4112x over previous
//
#include <hip/hip_runtime.h>

#define CH 256
#define KC 8192
#define NT 32768

#define TM 128         // tokens per block
#define TN 128         // codes per jt tile
#define BK 32          // channels staged per stage
#define LDK 40         // 32 + 8 pad halves (80 B row stride: conflict-free b128)

typedef _Float16 half4_t __attribute__((ext_vector_type(4)));
typedef _Float16 half8_t __attribute__((ext_vector_type(8)));
typedef float floatx4 __attribute__((ext_vector_type(4)));

// ---------------------------------------------------------------------------
// Kernel 1: codebook = ces / clip(usage, 1e-5); cbsq[k] = ||cb_k||^2.
// Also: EMA output init (new = (1-s)*old), zero loss accumulator, and
// init packed argmin keys to all-ones (atomicMin folds below this).
// ---------------------------------------------------------------------------
__global__ void k_codebook(const float* __restrict__ usage,
                           const float* __restrict__ ces,
                           float* __restrict__ cbook,
                           float* __restrict__ cbsq,
                           float* __restrict__ out_usage,
                           float* __restrict__ out_ces,
                           unsigned long long* __restrict__ packed,
                           float* __restrict__ loss_acc) {
    const float s = 0.01f;
    const float oms = 1.0f - s;
    int k = blockIdx.x;
    int c = threadIdx.x;
    float u  = usage[k];
    float uc = fmaxf(u, 1e-5f);
    float v  = ces[k * CH + c];
    float cb = v / uc;
    cbook[k * CH + c]   = cb;
    out_ces[k * CH + c] = oms * v;

    float p = cb * cb;
    #pragma unroll
    for (int off = 32; off; off >>= 1) p += __shfl_down(p, off);
    __shared__ float ps[4];
    int lane = c & 63, w = c >> 6;
    if (lane == 0) ps[w] = p;
    __syncthreads();
    if (c == 0) {
        cbsq[k] = ps[0] + ps[1] + ps[2] + ps[3];
        out_usage[k] = oms * u;
    }
    int gid = blockIdx.x * CH + c;
    if (gid < NT) packed[gid] = 0xFFFFFFFFFFFFFFFFull;
    if (gid == 0) loss_acc[0] = 0.0f;
}

// ---------------------------------------------------------------------------
// Kernel 2: fp16-split MFMA argmin.
// dot(x, cb) = xh*ch + xh*cl + xl*ch  (lo*lo dropped, ~2^-22 rel).
// Block: 256 thr (4 waves, 2x2), tile TM=128 tokens x TN=128 codes, BK=32.
// Each block covers one 128-token slice x one 4096-code half; results fold
// across blocks via atomicMin on ((flip(score)<<32)|code) -> min score,
// ties -> smallest code (matches jnp.argmin first-hit).
// ---------------------------------------------------------------------------
__launch_bounds__(256, 2)
__global__ void k_argmin(const float* __restrict__ emb,
                         const float* __restrict__ cbook,
                         const float* __restrict__ cbsq,
                         unsigned long long* __restrict__ packed) {
    __shared__ __align__(16) _Float16 As[2][TM][LDK];   // [split][token][k]
    __shared__ __align__(16) _Float16 Bs[2][TN][LDK];   // [split][code][k]
    __shared__ float cand_v[2][TM];
    __shared__ int   cand_i[2][TM];

    const int t    = threadIdx.x;
    const int lane = t & 63;
    const int wave = t >> 6;
    const int wx   = wave & 1;        // code half within tile (64 codes)
    const int wy   = wave >> 1;       // token half within tile (64 tokens)
    const int lr   = lane & 15;       // row within 16x16 frag
    const int ko   = (lane >> 4) * 8; // k offset within frag (quad*8)

    const int n0    = blockIdx.x * TM;
    const int jhalf = blockIdx.y * (KC / 2);

    float minv[16];
    int   mini[16];
    #pragma unroll
    for (int e = 0; e < 16; ++e) { minv[e] = 3.402823466e38f; mini[e] = 0; }

    for (int jt = 0; jt < (KC / 2); jt += TN) {
        const int jbase = jhalf + jt;

        floatx4 acc[4][4];
        #pragma unroll
        for (int mf = 0; mf < 4; ++mf)
            #pragma unroll
            for (int nf = 0; nf < 4; ++nf)
                acc[mf][nf] = (floatx4){0.f, 0.f, 0.f, 0.f};

        #pragma unroll 1
        for (int c0 = 0; c0 < CH; c0 += BK) {
            // ---- stage: load fp32, split to (hi,lo) fp16, store to LDS ----
            float4 av[4], bv[4];
            int rows[4], kcs[4];
            #pragma unroll
            for (int i = 0; i < 4; ++i) {
                int chunk = i * 256 + t;          // 0..1023
                int row   = chunk >> 3;           // 0..127
                int kc    = (chunk & 7) * 4;      // 0..28
                rows[i] = row; kcs[i] = kc;
                av[i] = *(const float4*)&emb  [(size_t)(n0    + row) * CH + c0 + kc];
                bv[i] = *(const float4*)&cbook[(size_t)(jbase + row) * CH + c0 + kc];
            }
            __syncthreads();   // previous stage's LDS reads complete
            #pragma unroll
            for (int i = 0; i < 4; ++i) {
                float va[4] = {av[i].x, av[i].y, av[i].z, av[i].w};
                float vb[4] = {bv[i].x, bv[i].y, bv[i].z, bv[i].w};
                half4_t ah, al, bh, bl;
                #pragma unroll
                for (int q = 0; q < 4; ++q) {
                    _Float16 h = (_Float16)va[q];
                    ah[q] = h; al[q] = (_Float16)(va[q] - (float)h);
                    _Float16 g = (_Float16)vb[q];
                    bh[q] = g; bl[q] = (_Float16)(vb[q] - (float)g);
                }
                *(half4_t*)&As[0][rows[i]][kcs[i]] = ah;
                *(half4_t*)&As[1][rows[i]][kcs[i]] = al;
                *(half4_t*)&Bs[0][rows[i]][kcs[i]] = bh;
                *(half4_t*)&Bs[1][rows[i]][kcs[i]] = bl;
            }
            __syncthreads();

            // ---- fragments + MFMA ----
            half8_t fah[4], fal[4], fbh[4], fbl[4];
            #pragma unroll
            for (int mf = 0; mf < 4; ++mf) {
                int row = wy * 64 + mf * 16 + lr;
                fah[mf] = *(const half8_t*)&As[0][row][ko];
                fal[mf] = *(const half8_t*)&As[1][row][ko];
            }
            #pragma unroll
            for (int nf = 0; nf < 4; ++nf) {
                int row = wx * 64 + nf * 16 + lr;
                fbh[nf] = *(const half8_t*)&Bs[0][row][ko];
                fbl[nf] = *(const half8_t*)&Bs[1][row][ko];
            }
            #pragma unroll
            for (int mf = 0; mf < 4; ++mf)
                #pragma unroll
                for (int nf = 0; nf < 4; ++nf) {
                    acc[mf][nf] = __builtin_amdgcn_mfma_f32_16x16x32_f16(
                        fah[mf], fbh[nf], acc[mf][nf], 0, 0, 0);
                    acc[mf][nf] = __builtin_amdgcn_mfma_f32_16x16x32_f16(
                        fah[mf], fbl[nf], acc[mf][nf], 0, 0, 0);
                    acc[mf][nf] = __builtin_amdgcn_mfma_f32_16x16x32_f16(
                        fal[mf], fbh[nf], acc[mf][nf], 0, 0, 0);
                }
        }

        // ---- fold this 128-code tile into per-lane running argmin ----
        // C/D layout: col(code) = lane&15, row(token) = (lane>>4)*4 + reg
        #pragma unroll
        for (int nf = 0; nf < 4; ++nf) {
            int j = jbase + wx * 64 + nf * 16 + lr;
            float sq = cbsq[j];
            #pragma unroll
            for (int mf = 0; mf < 4; ++mf) {
                floatx4 a = acc[mf][nf];
                #pragma unroll
                for (int r = 0; r < 4; ++r) {
                    float sc = sq - 2.0f * a[r];
                    int e = mf * 4 + r;
                    if (sc < minv[e]) { minv[e] = sc; mini[e] = j; }
                }
            }
        }
    }

    // ---- cross-lane argmin over the 16 code-columns in each quad group ----
    #pragma unroll
    for (int e = 0; e < 16; ++e) {
        float v = minv[e];
        int   x = mini[e];
        #pragma unroll
        for (int m = 1; m <= 8; m <<= 1) {
            float ov = __shfl_xor(v, m, 64);
            int   ox = __shfl_xor(x, m, 64);
            if (ov < v || (ov == v && ox < x)) { v = ov; x = ox; }
        }
        if (lr == 0) {
            int row = wy * 64 + (e >> 2) * 16 + (lane >> 4) * 4 + (e & 3);
            cand_v[wx][row] = v;
            cand_i[wx][row] = x;
        }
    }
    __syncthreads();

    if (t < TM) {
        float v0 = cand_v[0][t]; int i0 = cand_i[0][t];
        float v1 = cand_v[1][t]; int i1 = cand_i[1][t];
        if (v1 < v0 || (v1 == v0 && i1 < i0)) { v0 = v1; i0 = i1; }
        unsigned s = __float_as_uint(v0);
        s = (s & 0x80000000u) ? ~s : (s | 0x80000000u);   // order-preserving map
        unsigned long long key = ((unsigned long long)s << 32) | (unsigned)i0;
        atomicMin(&packed[n0 + t], key);
    }
}

// ---------------------------------------------------------------------------
// Kernel 3: gather + straight-through + loss partials + EMA scatter
// ---------------------------------------------------------------------------
__global__ void k_gather(const float* __restrict__ emb,
                         const float* __restrict__ cbook,
                         const unsigned long long* __restrict__ packed,
                         float* __restrict__ out_eq,
                         float* __restrict__ codes_f,
                         float* __restrict__ out_usage,
                         float* __restrict__ out_ces,
                         float* __restrict__ loss_acc) {
    const float s = 0.01f;
    int n = blockIdx.x;
    int c = threadIdx.x;
    int k = (int)(packed[n] & 0xFFFFFFFFull);
    float e  = emb[n * CH + c];
    float q  = cbook[k * CH + c];
    float eq = e + (q - e);
    out_eq[n * CH + c] = eq;
    atomicAdd(&out_ces[k * CH + c], s * e);

    float d = eq - e;
    float p = d * d;
    #pragma unroll
    for (int off = 32; off; off >>= 1) p += __shfl_down(p, off);
    __shared__ float ps[4];
    int lane = c & 63, w = c >> 6;
    if (lane == 0) ps[w] = p;
    __syncthreads();
    if (c == 0) {
        codes_f[n] = (float)k;
        atomicAdd(loss_acc, ps[0] + ps[1] + ps[2] + ps[3]);
        atomicAdd(&out_usage[k], s);
    }
}

// ---------------------------------------------------------------------------
// Kernel 4: finalize loss (mean over 2^23 elements)
// ---------------------------------------------------------------------------
__global__ void k_final(const float* __restrict__ loss_acc,
                        float* __restrict__ out_loss) {
    out_loss[0] = loss_acc[0] * (1.0f / 8388608.0f);
}

extern "C" void kernel_launch(void* const* d_in, const int* in_sizes, int n_in,
                              void* d_out, int out_size, void* d_ws, size_t ws_size,
                              hipStream_t stream) {
    const float* emb   = (const float*)d_in[0];  // [32768, 256]
    const float* usage = (const float*)d_in[1];  // [8192]
    const float* ces   = (const float*)d_in[2];  // [8192, 256]

    float* out      = (float*)d_out;
    float* o_codes  = out;                       // 32768
    float* o_eq     = out + NT;                  // 8388608
    float* o_loss   = o_eq + (size_t)NT * CH;    // 1
    float* o_usage  = o_loss + 1;                // 8192
    float* o_ces    = o_usage + KC;              // 2097152

    float* ws       = (float*)d_ws;
    float* cbook    = ws;                                    // KC*CH floats
    float* cbsq     = cbook + (size_t)KC * CH;               // KC floats
    unsigned long long* packed =
        (unsigned long long*)(cbsq + KC);                    // NT u64
    float* loss_acc = (float*)(packed + NT);                 // 1 float

    k_codebook<<<KC, CH, 0, stream>>>(usage, ces, cbook, cbsq,
                                      o_usage, o_ces, packed, loss_acc);
    dim3 agrid(NT / TM, 2);
    k_argmin<<<agrid, 256, 0, stream>>>(emb, cbook, cbsq, packed);
    k_gather<<<NT, CH, 0, stream>>>(emb, cbook, packed, o_eq, o_codes,
                                    o_usage, o_ces, loss_acc);
    k_final<<<1, 1, 0, stream>>>(loss_acc, o_loss);
}

// Round 3
// 723.884 us; speedup vs baseline: 3.3203x; 1.3770x over previous
//
#include <hip/hip_runtime.h>

#define CH 256
#define KC 8192
#define NT 32768

#define TM 128         // tokens per block
#define TN 128         // codes per jt tile
#define BK 32          // channels staged per stage
#define NS 256         // total pipeline stages = (KC/2/TN) * (CH/BK) = 32*8

typedef _Float16 half4_t __attribute__((ext_vector_type(4)));
typedef _Float16 half8_t __attribute__((ext_vector_type(8)));
typedef float floatx4 __attribute__((ext_vector_type(4)));

// XOR-swizzled LDS offset (halves) for row-major [row][BK] tiles, 16B chunks.
// chunk' = chunk ^ ((row>>1)&3): makes both staging writes and fragment reads
// hit 1 dword/bank/phase (conflict-free floor), no padding -> 16B aligned.
__device__ __forceinline__ int swz(int row, int chunk) {
    return row * BK + ((chunk ^ ((row >> 1) & 3)) << 3);
}

// ---------------------------------------------------------------------------
// Kernel 0: split embeddings fp32 -> (hi, lo) fp16 arrays
// ---------------------------------------------------------------------------
__global__ void k_split(const float* __restrict__ x,
                        _Float16* __restrict__ xh,
                        _Float16* __restrict__ xl) {
    int i = blockIdx.x * blockDim.x + threadIdx.x;   // one float4 per thread
    float4 v = ((const float4*)x)[i];
    float va[4] = {v.x, v.y, v.z, v.w};
    half4_t h, l;
    #pragma unroll
    for (int q = 0; q < 4; ++q) {
        _Float16 hh = (_Float16)va[q];
        h[q] = hh;
        l[q] = (_Float16)(va[q] - (float)hh);
    }
    ((half4_t*)xh)[i] = h;
    ((half4_t*)xl)[i] = l;
}

// ---------------------------------------------------------------------------
// Kernel 1: codebook row = ces/clip(usage); emit fp16 hi/lo split + cbsq,
// init EMA outputs (new = 0.99*old) and the packed argmin keys.
// ---------------------------------------------------------------------------
__global__ void k_codebook(const float* __restrict__ usage,
                           const float* __restrict__ ces,
                           _Float16* __restrict__ cbh,
                           _Float16* __restrict__ cbl,
                           float* __restrict__ cbsq,
                           float* __restrict__ out_usage,
                           float* __restrict__ out_ces,
                           unsigned long long* __restrict__ packed) {
    const float s = 0.01f;
    const float oms = 1.0f - s;
    int k = blockIdx.x;
    int c = threadIdx.x;
    float u  = usage[k];
    float uc = fmaxf(u, 1e-5f);
    float v  = ces[k * CH + c];
    float cb = v / uc;
    _Float16 h = (_Float16)cb;
    cbh[k * CH + c] = h;
    cbl[k * CH + c] = (_Float16)(cb - (float)h);
    out_ces[k * CH + c] = oms * v;

    float p = cb * cb;
    #pragma unroll
    for (int off = 32; off; off >>= 1) p += __shfl_down(p, off);
    __shared__ float ps[4];
    int lane = c & 63, w = c >> 6;
    if (lane == 0) ps[w] = p;
    __syncthreads();
    if (c == 0) {
        cbsq[k] = ps[0] + ps[1] + ps[2] + ps[3];
        out_usage[k] = oms * u;
    }
    int gid = blockIdx.x * CH + c;
    if (gid < NT) packed[gid] = 0xFFFFFFFFFFFFFFFFull;
}

// ---------------------------------------------------------------------------
// Kernel 2: fp16-split MFMA argmin, single-barrier double-buffered pipeline.
// dot = xh*ch + xh*cl + xl*ch (lo*lo dropped). 256 thr = 4 waves (2x2),
// block tile 128 tokens x 128 codes, 256 flattened stages (32 jt x 8 c0).
// ---------------------------------------------------------------------------
__launch_bounds__(256, 2)
__global__ void k_argmin(const _Float16* __restrict__ eh,
                         const _Float16* __restrict__ el,
                         const _Float16* __restrict__ cbh,
                         const _Float16* __restrict__ cbl,
                         const float* __restrict__ cbsq,
                         unsigned long long* __restrict__ packed) {
    // [buf][array: 0=Ah 1=Al 2=Bh 3=Bl][TM*BK halves] = 64 KiB
    __shared__ __align__(16) _Float16 sm[2][4][TM * BK];

    const int t    = threadIdx.x;
    const int lane = t & 63;
    const int wave = t >> 6;
    const int wx   = wave & 1;        // code half (64 codes)
    const int wy   = wave >> 1;       // token half (64 tokens)
    const int lr   = lane & 15;
    const int koq  = lane >> 4;       // k-chunk (quad) for fragments

    const int n0    = blockIdx.x * TM;
    const int jhalf = blockIdx.y * (KC / 2);

    // staging: thread covers row = t>>1, natural 16B chunks q0, q0+1
    const int srow = t >> 1;
    const int q0   = (t & 1) * 2;

    half8_t rAh[2], rAl[2], rBh[2], rBl[2];

    auto gload = [&](int s) {
        int c0 = (s & 7) * BK;
        int jb = jhalf + (s >> 3) * TN;
        size_t abase = (size_t)(n0 + srow) * CH + c0;
        size_t bbase = (size_t)(jb + srow) * CH + c0;
        #pragma unroll
        for (int i = 0; i < 2; ++i) {
            int kc = (q0 + i) * 8;
            rAh[i] = *(const half8_t*)(eh  + abase + kc);
            rAl[i] = *(const half8_t*)(el  + abase + kc);
            rBh[i] = *(const half8_t*)(cbh + bbase + kc);
            rBl[i] = *(const half8_t*)(cbl + bbase + kc);
        }
    };
    auto lstore = [&](int nb) {
        #pragma unroll
        for (int i = 0; i < 2; ++i) {
            int off = swz(srow, q0 + i);
            *(half8_t*)&sm[nb][0][off] = rAh[i];
            *(half8_t*)&sm[nb][1][off] = rAl[i];
            *(half8_t*)&sm[nb][2][off] = rBh[i];
            *(half8_t*)&sm[nb][3][off] = rBl[i];
        }
    };

    float minv[16];
    int   mini[16];
    #pragma unroll
    for (int e = 0; e < 16; ++e) { minv[e] = 3.402823466e38f; mini[e] = 0; }

    floatx4 acc[4][4];
    #pragma unroll
    for (int mf = 0; mf < 4; ++mf)
        #pragma unroll
        for (int nf = 0; nf < 4; ++nf)
            acc[mf][nf] = (floatx4){0.f, 0.f, 0.f, 0.f};

    gload(0);
    lstore(0);
    __syncthreads();

    #pragma unroll 1
    for (int s = 0; s < NS; ++s) {
        const int b = s & 1;
        if (s + 1 < NS) gload(s + 1);

        half8_t fah[4], fal[4];
        #pragma unroll
        for (int mf = 0; mf < 4; ++mf) {
            int off = swz(wy * 64 + mf * 16 + lr, koq);
            fah[mf] = *(const half8_t*)&sm[b][0][off];
            fal[mf] = *(const half8_t*)&sm[b][1][off];
        }
        #pragma unroll
        for (int nf = 0; nf < 4; ++nf) {
            int offb = swz(wx * 64 + nf * 16 + lr, koq);
            half8_t fbh = *(const half8_t*)&sm[b][2][offb];
            half8_t fbl = *(const half8_t*)&sm[b][3][offb];
            #pragma unroll
            for (int mf = 0; mf < 4; ++mf) {
                acc[mf][nf] = __builtin_amdgcn_mfma_f32_16x16x32_f16(
                    fah[mf], fbh, acc[mf][nf], 0, 0, 0);
                acc[mf][nf] = __builtin_amdgcn_mfma_f32_16x16x32_f16(
                    fah[mf], fbl, acc[mf][nf], 0, 0, 0);
                acc[mf][nf] = __builtin_amdgcn_mfma_f32_16x16x32_f16(
                    fal[mf], fbh, acc[mf][nf], 0, 0, 0);
            }
        }

        if ((s & 7) == 7) {   // end of a jt tile: fold scores, reset acc
            int jbase = jhalf + (s >> 3) * TN;
            #pragma unroll
            for (int nf = 0; nf < 4; ++nf) {
                int j = jbase + wx * 64 + nf * 16 + lr;
                float sq = cbsq[j];
                #pragma unroll
                for (int mf = 0; mf < 4; ++mf) {
                    floatx4 a = acc[mf][nf];
                    #pragma unroll
                    for (int r = 0; r < 4; ++r) {
                        float sc = sq - 2.0f * a[r];
                        int e = mf * 4 + r;
                        if (sc < minv[e]) { minv[e] = sc; mini[e] = j; }
                    }
                    acc[mf][nf] = (floatx4){0.f, 0.f, 0.f, 0.f};
                }
            }
        }

        if (s + 1 < NS) lstore((s + 1) & 1);
        __syncthreads();   // single barrier per stage
    }

    // epilogue: reduce 16 code-columns per quad group, then across tx/waves.
    // cand arrays alias the (now dead) LDS buffers.
    float* cand_v = (float*)&sm[0][0][0];   // [2][TM]
    int*   cand_i = (int*)  &sm[0][2][0];   // [2][TM]

    #pragma unroll
    for (int e = 0; e < 16; ++e) {
        float v = minv[e];
        int   x = mini[e];
        #pragma unroll
        for (int m = 1; m <= 8; m <<= 1) {
            float ov = __shfl_xor(v, m, 64);
            int   ox = __shfl_xor(x, m, 64);
            if (ov < v || (ov == v && ox < x)) { v = ov; x = ox; }
        }
        if (lr == 0) {
            int row = wy * 64 + (e >> 2) * 16 + (lane >> 4) * 4 + (e & 3);
            cand_v[wx * TM + row] = v;
            cand_i[wx * TM + row] = x;
        }
    }
    __syncthreads();

    if (t < TM) {
        float v0 = cand_v[t];      int i0 = cand_i[t];
        float v1 = cand_v[TM + t]; int i1 = cand_i[TM + t];
        if (v1 < v0 || (v1 == v0 && i1 < i0)) { v0 = v1; i0 = i1; }
        unsigned sb = __float_as_uint(v0);
        sb = (sb & 0x80000000u) ? ~sb : (sb | 0x80000000u);
        unsigned long long key = ((unsigned long long)sb << 32) | (unsigned)i0;
        atomicMin(&packed[n0 + t], key);
    }
}

// ---------------------------------------------------------------------------
// Kernel 3: gather + straight-through + loss partials + EMA scatter.
// 4 tokens per block (one wave each), float4 per lane. Codebook row is
// recomputed as ces[k]/clip(usage[k]) (same fp32 division as reference).
// ---------------------------------------------------------------------------
__global__ void k_gather(const float* __restrict__ emb,
                         const float* __restrict__ ces,
                         const float* __restrict__ usage,
                         const unsigned long long* __restrict__ packed,
                         float* __restrict__ out_eq,
                         float* __restrict__ codes_f,
                         float* __restrict__ out_usage,
                         float* __restrict__ out_ces,
                         float* __restrict__ partials) {
    const float s = 0.01f;
    int t = threadIdx.x;
    int wave = t >> 6, lane = t & 63;
    int n = blockIdx.x * 4 + wave;
    int k = (int)(packed[n] & 0xFFFFFFFFull);
    float uc = fmaxf(usage[k], 1e-5f);
    int c = lane * 4;

    float4 e = *(const float4*)&emb[(size_t)n * CH + c];
    float4 v = *(const float4*)&ces[(size_t)k * CH + c];
    float ea[4] = {e.x, e.y, e.z, e.w};
    float va[4] = {v.x, v.y, v.z, v.w};
    float eqa[4];
    float p = 0.0f;
    #pragma unroll
    for (int q = 0; q < 4; ++q) {
        float cb = va[q] / uc;
        float eq = ea[q] + (cb - ea[q]);
        eqa[q] = eq;
        float d = eq - ea[q];
        p += d * d;
        atomicAdd(&out_ces[(size_t)k * CH + c + q], s * ea[q]);
    }
    *(float4*)&out_eq[(size_t)n * CH + c] =
        (float4){eqa[0], eqa[1], eqa[2], eqa[3]};

    #pragma unroll
    for (int off = 32; off; off >>= 1) p += __shfl_down(p, off);
    __shared__ float ps[4];
    if (lane == 0) {
        ps[wave] = p;
        codes_f[n] = (float)k;
        atomicAdd(&out_usage[k], s);
    }
    __syncthreads();
    if (t == 0) partials[blockIdx.x] = ps[0] + ps[1] + ps[2] + ps[3];
}

// ---------------------------------------------------------------------------
// Kernel 4: reduce loss partials (8192 floats), mean over 2^23 elements
// ---------------------------------------------------------------------------
__global__ void k_final(const float* __restrict__ partials,
                        float* __restrict__ out_loss) {
    int t = threadIdx.x;
    float p = 0.0f;
    for (int i = t; i < 8192; i += 256) p += partials[i];
    #pragma unroll
    for (int off = 32; off; off >>= 1) p += __shfl_down(p, off);
    __shared__ float ps[4];
    if ((t & 63) == 0) ps[t >> 6] = p;
    __syncthreads();
    if (t == 0)
        out_loss[0] = (ps[0] + ps[1] + ps[2] + ps[3]) * (1.0f / 8388608.0f);
}

extern "C" void kernel_launch(void* const* d_in, const int* in_sizes, int n_in,
                              void* d_out, int out_size, void* d_ws, size_t ws_size,
                              hipStream_t stream) {
    const float* emb   = (const float*)d_in[0];  // [32768, 256]
    const float* usage = (const float*)d_in[1];  // [8192]
    const float* ces   = (const float*)d_in[2];  // [8192, 256]

    float* out      = (float*)d_out;
    float* o_codes  = out;                       // 32768
    float* o_eq     = out + NT;                  // 8388608
    float* o_loss   = o_eq + (size_t)NT * CH;    // 1
    float* o_usage  = o_loss + 1;                // 8192
    float* o_ces    = o_usage + KC;              // 2097152

    // ws layout (8B-aligned first)
    unsigned long long* packed = (unsigned long long*)d_ws;   // NT u64
    float* cbsq     = (float*)(packed + NT);                  // KC
    float* partials = cbsq + KC;                              // 8192
    _Float16* eh  = (_Float16*)(partials + 8192);             // NT*CH
    _Float16* el  = eh + (size_t)NT * CH;
    _Float16* cbh = el + (size_t)NT * CH;                     // KC*CH
    _Float16* cbl = cbh + (size_t)KC * CH;

    k_split<<<NT * CH / 1024, 256, 0, stream>>>(emb, eh, el);
    k_codebook<<<KC, CH, 0, stream>>>(usage, ces, cbh, cbl, cbsq,
                                      o_usage, o_ces, packed);
    dim3 agrid(NT / TM, 2);
    k_argmin<<<agrid, 256, 0, stream>>>(eh, el, cbh, cbl, cbsq, packed);
    k_gather<<<NT / 4, 256, 0, stream>>>(emb, ces, usage, packed, o_eq,
                                         o_codes, o_usage, o_ces, partials);
    k_final<<<1, 256, 0, stream>>>(partials, o_loss);
}